// Round 15
// baseline (8714.157 us; speedup 1.0000x reference)
//
#include <hip/hip_runtime.h>

// DownSampling: B=16, N=16384, C=128, M=4096. f32 in/out.
// LOCKED ORACLE SEMANTICS (R14, absmax==0): per point,
//   dx=px-cx; dy=py-cy; dz=pz-cz;
//   d = fma(dz,dz, fma(dx,dx, rn(dy*dy)))   [XLA-GPU tree contraction]
//   dist = min(dist, d); argmax with FIRST-index tie-break at every level.
// R15: VALU-issue-bound (87% on active CUs). Fixes: (1) explicit named v2f
// registers (R14's VGPR_Count=44 < 64 floats of state => arrays weren't in
// arch VGPRs); (2) packed VOP3P f32 (v_pk_* are IEEE RN per half == scalar
// ops bitwise; sub via exact pre-negated centroid); (3) ds_swizzle argmax
// butterflies + readfirstlane broadcast.
#define B_   16
#define N_   16384
#define C_   128
#define M_   4096
#define TPB  1024

typedef float v2f __attribute__((ext_vector_type(2)));

__device__ __forceinline__ v2f pk_add(v2f a, v2f b){ v2f d; asm("v_pk_add_f32 %0, %1, %2" : "=v"(d) : "v"(a), "v"(b)); return d; }
__device__ __forceinline__ v2f pk_mul(v2f a, v2f b){ v2f d; asm("v_pk_mul_f32 %0, %1, %2" : "=v"(d) : "v"(a), "v"(b)); return d; }
__device__ __forceinline__ v2f pk_fma3(v2f a, v2f b, v2f c){ v2f d; asm("v_pk_fma_f32 %0, %1, %2, %3" : "=v"(d) : "v"(a), "v"(b), "v"(c)); return d; }

// load one row (x, y, or z) of 16 consecutive floats into 8 named v2f pairs
#define LOADROW(P0,P1,P2,P3,P4,P5,P6,P7, BASE) do{                                 \
    const float4* _r4 = reinterpret_cast<const float4*>(BASE);                     \
    float4 _A0=_r4[t*4+0], _A1=_r4[t*4+1], _A2=_r4[t*4+2], _A3=_r4[t*4+3];         \
    P0=(v2f){_A0.x,_A0.y}; P1=(v2f){_A0.z,_A0.w};                                  \
    P2=(v2f){_A1.x,_A1.y}; P3=(v2f){_A1.z,_A1.w};                                  \
    P4=(v2f){_A2.x,_A2.y}; P5=(v2f){_A2.z,_A2.w};                                  \
    P6=(v2f){_A3.x,_A3.y}; P7=(v2f){_A3.z,_A3.w};                                  \
}while(0)

// one point-pair distance update + argmax tracking (slots S0<S1, sequential
// so strict '>' keeps first-index tie-break)
#define DSTEP(AX,AY,AZ,DD,S0,S1) do{                                               \
    v2f _dx = pk_add(AX, mcx);                                                     \
    v2f _dy = pk_add(AY, mcy);                                                     \
    v2f _dz = pk_add(AZ, mcz);                                                     \
    v2f _q  = pk_fma3(_dz, _dz, pk_fma3(_dx, _dx, pk_mul(_dy, _dy)));              \
    float _n0 = fminf(DD.x, _q.x); DD.x = _n0;                                     \
    bool _c0 = _n0 > bmax; bmax = _c0 ? _n0 : bmax; bslot = _c0 ? (S0) : bslot;    \
    float _n1 = fminf(DD.y, _q.y); DD.y = _n1;                                     \
    bool _c1 = _n1 > bmax; bmax = _c1 ? _n1 : bmax; bslot = _c1 ? (S1) : bslot;    \
}while(0)

// argmax butterfly step via ds_swizzle (xor within 32-lane halves)
#define AMAXSTEP(V,I,PAT) do{                                                      \
    float _ov = __int_as_float(__builtin_amdgcn_ds_swizzle(__float_as_int(V), PAT));\
    int   _oi = __builtin_amdgcn_ds_swizzle(I, PAT);                               \
    bool _tk = (_ov > V) || ((_ov == V) && (_oi < I));                             \
    V = _tk ? _ov : V; I = _tk ? _oi : I;                                          \
}while(0)

__global__ __launch_bounds__(TPB, 4) void fps_kernel(const float* __restrict__ xyz,
                                                     int* __restrict__ idx_out)
{
    const int b = blockIdx.x;
    const int t = threadIdx.x;
    const int wid  = t >> 6;
    const int lane = t & 63;
    const float* xb = xyz + (size_t)b * 3 * N_;

    // 16 consecutive points per thread, fully in named registers.
    v2f ax0,ax1,ax2,ax3,ax4,ax5,ax6,ax7;
    v2f ay0,ay1,ay2,ay3,ay4,ay5,ay6,ay7;
    v2f az0,az1,az2,az3,az4,az5,az6,az7;
    LOADROW(ax0,ax1,ax2,ax3,ax4,ax5,ax6,ax7, xb);
    LOADROW(ay0,ay1,ay2,ay3,ay4,ay5,ay6,ay7, xb + N_);
    LOADROW(az0,az1,az2,az3,az4,az5,az6,az7, xb + 2 * N_);

    v2f dd0 = (v2f){1e10f,1e10f}, dd1 = dd0, dd2 = dd0, dd3 = dd0,
        dd4 = dd0, dd5 = dd0, dd6 = dd0, dd7 = dd0;   // BIG sentinel

    __shared__ float lv[2][16];
    __shared__ int   li[2][16];

    if (t == 0) idx_out[b * M_ + 0] = 0;   // deterministic start at index 0

    float cx = xb[0], cy = xb[N_], cz = xb[2 * N_];

    for (int m = 1; m < M_; ++m) {
        // exact negation -> pk_add(p, -c) == p - c bitwise
        v2f mcx = (v2f){-cx,-cx}, mcy = (v2f){-cy,-cy}, mcz = (v2f){-cz,-cz};

        float bmax = -1.0f;
        int bslot = 0;
        DSTEP(ax0,ay0,az0,dd0, 0, 1);
        DSTEP(ax1,ay1,az1,dd1, 2, 3);
        DSTEP(ax2,ay2,az2,dd2, 4, 5);
        DSTEP(ax3,ay3,az3,dd3, 6, 7);
        DSTEP(ax4,ay4,az4,dd4, 8, 9);
        DSTEP(ax5,ay5,az5,dd5,10,11);
        DSTEP(ax6,ay6,az6,dd6,12,13);
        DSTEP(ax7,ay7,az7,dd7,14,15);
        int gidx = t * 16 + bslot;

        // wave argmax: 5 swizzle steps within 32-lane halves, then xor-32
        AMAXSTEP(bmax, gidx, 0x041f);
        AMAXSTEP(bmax, gidx, 0x081f);
        AMAXSTEP(bmax, gidx, 0x101f);
        AMAXSTEP(bmax, gidx, 0x201f);
        AMAXSTEP(bmax, gidx, 0x401f);
        {
            float ov = __shfl_xor(bmax, 32);
            int   oi = __shfl_xor(gidx, 32);
            bool tk = (ov > bmax) || ((ov == bmax) && (oi < gidx));
            bmax = tk ? ov : bmax;
            gidx = tk ? oi : gidx;
        }

        // cross-wave reduce via double-buffered LDS, single barrier
        const int buf = m & 1;
        if (lane == 0) { lv[buf][wid] = bmax; li[buf][wid] = gidx; }
        __syncthreads();
        float v  = (lane < 16) ? lv[buf][lane] : -1.0f;
        int   gi = (lane < 16) ? li[buf][lane] : 0x7fffffff;
        AMAXSTEP(v, gi, 0x041f);
        AMAXSTEP(v, gi, 0x081f);
        AMAXSTEP(v, gi, 0x101f);
        AMAXSTEP(v, gi, 0x201f);
        int j = __builtin_amdgcn_readfirstlane(gi);   // lane0 holds the reduce

        if (t == 0) idx_out[b * M_ + m] = j;

        // next centroid: same-address broadcast load (L2-resident)
        cx = xb[j];
        cy = xb[N_ + j];
        cz = xb[2 * N_ + j];
    }
}

// -------------------------------------------------------------------------
// Gather kernel: one block per (batch, output row). Rows 0..2 = xyz, 3..130 =
// feature channels. Raw f32 passthrough of gathered values.
// -------------------------------------------------------------------------
__global__ void gather_kernel(const float* __restrict__ xyz,
                              const float* __restrict__ feat,
                              const int*   __restrict__ idx,
                              float*       __restrict__ out)
{
    const int blk = blockIdx.x;
    const int b = blk / (3 + C_);
    const int r = blk % (3 + C_);
    const int* idb = idx + b * M_;

    if (r < 3) {
        const float* src = xyz + ((size_t)b * 3 + r) * N_;
        float*       dst = out + ((size_t)b * 3 + r) * M_;
        for (int m = threadIdx.x; m < M_; m += blockDim.x)
            dst[m] = src[idb[m]];
    } else {
        const int c = r - 3;
        const float* src = feat + ((size_t)b * C_ + c) * N_;
        float*       dst = out + (size_t)B_ * 3 * M_ + ((size_t)b * C_ + c) * M_;
        for (int m = threadIdx.x; m < M_; m += blockDim.x)
            dst[m] = src[idb[m]];
    }
}

extern "C" void kernel_launch(void* const* d_in, const int* in_sizes, int n_in,
                              void* d_out, int out_size, void* d_ws, size_t ws_size,
                              hipStream_t stream)
{
    const float* xyz  = (const float*)d_in[0];   // [16, 3, 16384] f32
    const float* feat = (const float*)d_in[1];   // [16, 128, 16384] f32
    float* out = (float*)d_out;                  // [16*3*4096] + [16*128*4096] f32
    int*   idx = (int*)d_ws;                     // [16, 4096] int32 scratch

    fps_kernel<<<dim3(B_), dim3(TPB), 0, stream>>>(xyz, idx);
    gather_kernel<<<dim3(B_ * (3 + C_)), dim3(256), 0, stream>>>(xyz, feat, idx, out);
}

// Round 16
// 8195.987 us; speedup vs baseline: 1.0632x; 1.0632x over previous
//
#include <hip/hip_runtime.h>

// DownSampling: B=16, N=16384, C=128, M=4096. f32 in/out.
// LOCKED ORACLE SEMANTICS (R14, absmax==0): per point,
//   dx=px-cx; dy=py-cy; dz=pz-cz;
//   d = fma(dz,dz, fma(dx,dx, rn(dy*dy)))   [XLA-GPU tree contraction]
//   dist = min(dist, d); argmax FIRST-index tie-break at every level.
// R16: R15 post-mortem — inline-asm arithmetic serialized and state never
// reached arch VGPRs (VGPR_Count 48 < 64 floats of state). This round:
// plain-C ext_vector packed math (v_pk_* via elementwise builtins, bitwise
// == scalar RN; p+(-c) == p-c exactly) + empty-asm register PINs to force
// coords/dist into arch VGPRs and forbid per-iteration reload.
#define B_   16
#define N_   16384
#define C_   128
#define M_   4096
#define TPB  1024

typedef float v2f __attribute__((ext_vector_type(2)));

// load one row (x, y, or z) of 16 consecutive floats into 8 named v2f pairs
#define LOADROW(P0,P1,P2,P3,P4,P5,P6,P7, BASE) do{                                 \
    const float4* _r4 = reinterpret_cast<const float4*>(BASE);                     \
    float4 _A0=_r4[t*4+0], _A1=_r4[t*4+1], _A2=_r4[t*4+2], _A3=_r4[t*4+3];         \
    P0=(v2f){_A0.x,_A0.y}; P1=(v2f){_A0.z,_A0.w};                                  \
    P2=(v2f){_A1.x,_A1.y}; P3=(v2f){_A1.z,_A1.w};                                  \
    P4=(v2f){_A2.x,_A2.y}; P5=(v2f){_A2.z,_A2.w};                                  \
    P6=(v2f){_A3.x,_A3.y}; P7=(v2f){_A3.z,_A3.w};                                  \
}while(0)

// one point-pair distance update + argmax tracking (slots S0<S1, sequential
// scan with strict '>' keeps first-index tie-break)
#define DSTEP(AX,AY,AZ,DD,S0,S1) do{                                               \
    v2f _dx = AX + mcx;                                                            \
    v2f _dy = AY + mcy;                                                            \
    v2f _dz = AZ + mcz;                                                            \
    v2f _q  = __builtin_elementwise_fma(_dz, _dz,                                  \
                 __builtin_elementwise_fma(_dx, _dx, _dy * _dy));                  \
    v2f _nd = __builtin_elementwise_min(DD, _q);                                   \
    DD = _nd;                                                                      \
    bool _c0 = _nd[0] > bmax; bmax = _c0 ? _nd[0] : bmax; bslot = _c0 ? (S0) : bslot; \
    bool _c1 = _nd[1] > bmax; bmax = _c1 ? _nd[1] : bmax; bslot = _c1 ? (S1) : bslot; \
}while(0)

// argmax butterfly step via ds_swizzle (xor within 32-lane halves) — verified
// bit-exact in R15 (passed absmax 0).
#define AMAXSTEP(V,I,PAT) do{                                                      \
    float _ov = __int_as_float(__builtin_amdgcn_ds_swizzle(__float_as_int(V), PAT));\
    int   _oi = __builtin_amdgcn_ds_swizzle(I, PAT);                               \
    bool _tk = (_ov > V) || ((_ov == V) && (_oi < I));                             \
    V = _tk ? _ov : V; I = _tk ? _oi : I;                                          \
}while(0)

__global__ __launch_bounds__(TPB) void fps_kernel(const float* __restrict__ xyz,
                                                  int* __restrict__ idx_out)
{
    const int b = blockIdx.x;
    const int t = threadIdx.x;
    const int wid  = t >> 6;
    const int lane = t & 63;
    const float* xb = xyz + (size_t)b * 3 * N_;

    // 16 consecutive points per thread, in named v2f registers.
    v2f ax0,ax1,ax2,ax3,ax4,ax5,ax6,ax7;
    v2f ay0,ay1,ay2,ay3,ay4,ay5,ay6,ay7;
    v2f az0,az1,az2,az3,az4,az5,az6,az7;
    LOADROW(ax0,ax1,ax2,ax3,ax4,ax5,ax6,ax7, xb);
    LOADROW(ay0,ay1,ay2,ay3,ay4,ay5,ay6,ay7, xb + N_);
    LOADROW(az0,az1,az2,az3,az4,az5,az6,az7, xb + 2 * N_);

    v2f d0 = (v2f){1e10f,1e10f}, d1 = d0, d2 = d0, d3 = d0,
        d4 = d0, d5 = d0, d6 = d0, d7 = d0;   // BIG sentinel

    __shared__ float lv[2][16];
    __shared__ int   li[2][16];

    if (t == 0) idx_out[b * M_ + 0] = 0;   // deterministic start at index 0

    float cx = xb[0], cy = xb[N_], cz = xb[2 * N_];

    for (int m = 1; m < M_; ++m) {
        // PIN: force coords + dist to live in arch VGPRs (emits no code,
        // forbids reload/remat — the R14/R15 pathology).
        asm volatile("" : "+v"(ax0),"+v"(ax1),"+v"(ax2),"+v"(ax3),
                          "+v"(ax4),"+v"(ax5),"+v"(ax6),"+v"(ax7),
                          "+v"(ay0),"+v"(ay1),"+v"(ay2),"+v"(ay3),
                          "+v"(ay4),"+v"(ay5),"+v"(ay6),"+v"(ay7),
                          "+v"(az0),"+v"(az1),"+v"(az2),"+v"(az3),
                          "+v"(az4),"+v"(az5),"+v"(az6),"+v"(az7));
        asm volatile("" : "+v"(d0),"+v"(d1),"+v"(d2),"+v"(d3),
                          "+v"(d4),"+v"(d5),"+v"(d6),"+v"(d7));

        // exact negation -> p + (-c) == p - c bitwise (IEEE RN)
        v2f mcx = (v2f){-cx,-cx}, mcy = (v2f){-cy,-cy}, mcz = (v2f){-cz,-cz};

        float bmax = -1.0f;
        int bslot = 0;
        DSTEP(ax0,ay0,az0,d0, 0, 1);
        DSTEP(ax1,ay1,az1,d1, 2, 3);
        DSTEP(ax2,ay2,az2,d2, 4, 5);
        DSTEP(ax3,ay3,az3,d3, 6, 7);
        DSTEP(ax4,ay4,az4,d4, 8, 9);
        DSTEP(ax5,ay5,az5,d5,10,11);
        DSTEP(ax6,ay6,az6,d6,12,13);
        DSTEP(ax7,ay7,az7,d7,14,15);
        int gidx = t * 16 + bslot;

        // wave argmax: 5 swizzle steps within 32-lane halves, then xor-32
        AMAXSTEP(bmax, gidx, 0x041f);
        AMAXSTEP(bmax, gidx, 0x081f);
        AMAXSTEP(bmax, gidx, 0x101f);
        AMAXSTEP(bmax, gidx, 0x201f);
        AMAXSTEP(bmax, gidx, 0x401f);
        {
            float ov = __shfl_xor(bmax, 32);
            int   oi = __shfl_xor(gidx, 32);
            bool tk = (ov > bmax) || ((ov == bmax) && (oi < gidx));
            bmax = tk ? ov : bmax;
            gidx = tk ? oi : gidx;
        }

        // cross-wave reduce via double-buffered LDS, single barrier
        const int buf = m & 1;
        if (lane == 0) { lv[buf][wid] = bmax; li[buf][wid] = gidx; }
        __syncthreads();
        float v  = (lane < 16) ? lv[buf][lane] : -1.0f;
        int   gi = (lane < 16) ? li[buf][lane] : 0x7fffffff;
        AMAXSTEP(v, gi, 0x041f);
        AMAXSTEP(v, gi, 0x081f);
        AMAXSTEP(v, gi, 0x101f);
        AMAXSTEP(v, gi, 0x201f);
        int j = __builtin_amdgcn_readfirstlane(gi);

        if (t == 0) idx_out[b * M_ + m] = j;

        // next centroid: uniform (SGPR) broadcast loads, L1/L2-resident
        cx = xb[j];
        cy = xb[N_ + j];
        cz = xb[2 * N_ + j];
    }
}

// -------------------------------------------------------------------------
// Gather kernel: one block per (batch, output row). Rows 0..2 = xyz, 3..130 =
// feature channels. Raw f32 passthrough of gathered values.
// -------------------------------------------------------------------------
__global__ void gather_kernel(const float* __restrict__ xyz,
                              const float* __restrict__ feat,
                              const int*   __restrict__ idx,
                              float*       __restrict__ out)
{
    const int blk = blockIdx.x;
    const int b = blk / (3 + C_);
    const int r = blk % (3 + C_);
    const int* idb = idx + b * M_;

    if (r < 3) {
        const float* src = xyz + ((size_t)b * 3 + r) * N_;
        float*       dst = out + ((size_t)b * 3 + r) * M_;
        for (int m = threadIdx.x; m < M_; m += blockDim.x)
            dst[m] = src[idb[m]];
    } else {
        const int c = r - 3;
        const float* src = feat + ((size_t)b * C_ + c) * N_;
        float*       dst = out + (size_t)B_ * 3 * M_ + ((size_t)b * C_ + c) * M_;
        for (int m = threadIdx.x; m < M_; m += blockDim.x)
            dst[m] = src[idb[m]];
    }
}

extern "C" void kernel_launch(void* const* d_in, const int* in_sizes, int n_in,
                              void* d_out, int out_size, void* d_ws, size_t ws_size,
                              hipStream_t stream)
{
    const float* xyz  = (const float*)d_in[0];   // [16, 3, 16384] f32
    const float* feat = (const float*)d_in[1];   // [16, 128, 16384] f32
    float* out = (float*)d_out;                  // [16*3*4096] + [16*128*4096] f32
    int*   idx = (int*)d_ws;                     // [16, 4096] int32 scratch

    fps_kernel<<<dim3(B_), dim3(TPB), 0, stream>>>(xyz, idx);
    gather_kernel<<<dim3(B_ * (3 + C_)), dim3(256), 0, stream>>>(xyz, feat, idx, out);
}

// Round 17
// 7181.734 us; speedup vs baseline: 1.2134x; 1.1412x over previous
//
#include <hip/hip_runtime.h>

// DownSampling: B=16, N=16384, C=128, M=4096. f32 in/out.
// LOCKED ORACLE SEMANTICS (R14, absmax==0): per point,
//   dx=px-cx; dy=py-cy; dz=pz-cz;
//   d = fma(dz,dz, fma(dx,dx, rn(dy*dy)))   [XLA-GPU tree contraction]
//   dist = min(dist, d); argmax = (max value, MIN index) at every level.
// R17: kernel is serial-latency-bound (R15/R16: fewer insts, slower).
// Tail surgery: DPP-based argmax butterflies (VALU pipe, ~5cyc vs ~70 for
// ds_swizzle) — the (max,min-idx) semilattice is order-independent, so
// mirror/quad_perm combining trees are bit-exact. Only 2 LDS-pipe ops left
// in the wave reduce; level-2 is pure DPP. Centroid reload via
// readfirstlane -> uniform s_load. Distance phase = R14 verbatim.
#define B_   16
#define N_   16384
#define C_   128
#define M_   4096
#define TPB  1024
#define PPT  16   // points per thread: TPB*PPT == N_

// one (max,min-idx) join step via DPP permutation (compile-time ctrl)
#define AMAX_DPP(V, I, CTRL) do{                                                    \
    float _ov = __int_as_float(__builtin_amdgcn_mov_dpp(__float_as_int(V),          \
                                                        (CTRL), 0xF, 0xF, 0));     \
    int   _oi = __builtin_amdgcn_mov_dpp((I), (CTRL), 0xF, 0xF, 0);                 \
    bool _tk = (_ov > (V)) || ((_ov == (V)) && (_oi < (I)));                        \
    (V) = _tk ? _ov : (V);  (I) = _tk ? _oi : (I);                                  \
}while(0)

// one join step via ds_swizzle xor pattern (within 32-lane groups)
#define AMAX_SWZ(V, I, PAT) do{                                                     \
    float _ov = __int_as_float(__builtin_amdgcn_ds_swizzle(__float_as_int(V), PAT));\
    int   _oi = __builtin_amdgcn_ds_swizzle((I), (PAT));                            \
    bool _tk = (_ov > (V)) || ((_ov == (V)) && (_oi < (I)));                        \
    (V) = _tk ? _ov : (V);  (I) = _tk ? _oi : (I);                                  \
}while(0)

#define DPP_QUAD_XOR1   0xB1   // quad_perm [1,0,3,2]
#define DPP_QUAD_XOR2   0x4E   // quad_perm [2,3,0,1]
#define DPP_HALF_MIRROR 0x141  // mirror within 8-lane half-rows
#define DPP_ROW_MIRROR  0x140  // mirror within 16-lane rows
#define SWZ_XOR16       0x401F // BitMode xor-16 within 32-lane groups

__global__ __launch_bounds__(TPB, 4) void fps_kernel(const float* __restrict__ xyz,
                                                     int* __restrict__ idx_out)
{
    const int b = blockIdx.x;
    const int t = threadIdx.x;
    const int wid  = t >> 6;
    const int lane = t & 63;
    const float* xb = xyz + (size_t)b * 3 * N_;

    float px[PPT], py[PPT], pz[PPT], dist[PPT];

    // Load 16 consecutive points per thread (float4-vectorized, coalesced).
    {
        const float4* x4 = reinterpret_cast<const float4*>(xb);
        const float4* y4 = reinterpret_cast<const float4*>(xb + N_);
        const float4* z4 = reinterpret_cast<const float4*>(xb + 2 * N_);
        #pragma unroll
        for (int q = 0; q < 4; ++q) {
            float4 vx = x4[t * 4 + q];
            float4 vy = y4[t * 4 + q];
            float4 vz = z4[t * 4 + q];
            px[q*4+0] = vx.x; px[q*4+1] = vx.y; px[q*4+2] = vx.z; px[q*4+3] = vx.w;
            py[q*4+0] = vy.x; py[q*4+1] = vy.y; py[q*4+2] = vy.z; py[q*4+3] = vy.w;
            pz[q*4+0] = vz.x; pz[q*4+1] = vz.y; pz[q*4+2] = vz.z; pz[q*4+3] = vz.w;
        }
    }
    #pragma unroll
    for (int i = 0; i < PPT; ++i) dist[i] = 1e10f;  // BIG sentinel

    __shared__ float lv[2][16];
    __shared__ int   li[2][16];

    if (t == 0) idx_out[b * M_ + 0] = 0;   // deterministic start at index 0

    // First centroid = point 0.
    float cx = xb[0], cy = xb[N_], cz = xb[2 * N_];

    for (int m = 1; m < M_; ++m) {
        // ---- distance phase: R14 verbatim (locked bit-exact semantics)
        float bmax = -1.0f;
        int bslot = 0;
        #pragma unroll
        for (int i = 0; i < PPT; ++i) {
            float dx = __fsub_rn(px[i], cx);
            float dy = __fsub_rn(py[i], cy);
            float dz = __fsub_rn(pz[i], cz);
            float inner = fmaf(dx, dx, __fmul_rn(dy, dy));
            float d     = fmaf(dz, dz, inner);
            float nd = fminf(dist[i], d);
            dist[i] = nd;
            bool c = nd > bmax;   // strict > => smallest slot wins ties
            bmax  = c ? nd : bmax;
            bslot = c ? i  : bslot;
        }
        int gidx = t * PPT + bslot;

        // ---- wave argmax: 4 DPP joins (VALU pipe) + xor16 swizzle + xor32
        AMAX_DPP(bmax, gidx, DPP_QUAD_XOR1);
        AMAX_DPP(bmax, gidx, DPP_QUAD_XOR2);
        AMAX_DPP(bmax, gidx, DPP_HALF_MIRROR);
        AMAX_DPP(bmax, gidx, DPP_ROW_MIRROR);
        AMAX_SWZ(bmax, gidx, SWZ_XOR16);
        {
            float ov = __shfl_xor(bmax, 32);
            int   oi = __shfl_xor(gidx, 32);
            bool tk = (ov > bmax) || ((ov == bmax) && (oi < gidx));
            bmax = tk ? ov : bmax;
            gidx = tk ? oi : gidx;
        }

        // ---- cross-wave reduce: LDS partials, single barrier, pure-DPP level 2
        const int buf = m & 1;
        if (lane == 0) { lv[buf][wid] = bmax; li[buf][wid] = gidx; }
        __syncthreads();
        float v  = (lane < 16) ? lv[buf][lane] : -1.0f;
        int   gi = (lane < 16) ? li[buf][lane] : 0x7fffffff;
        AMAX_DPP(v, gi, DPP_QUAD_XOR1);
        AMAX_DPP(v, gi, DPP_QUAD_XOR2);
        AMAX_DPP(v, gi, DPP_HALF_MIRROR);
        AMAX_DPP(v, gi, DPP_ROW_MIRROR);
        int j = __builtin_amdgcn_readfirstlane(gi);   // uniform -> s_load below

        if (t == 0) idx_out[b * M_ + m] = j;

        // next centroid: uniform scalar loads (L1/L2-resident)
        cx = xb[j];
        cy = xb[N_ + j];
        cz = xb[2 * N_ + j];
    }
}

// -------------------------------------------------------------------------
// Gather kernel: one block per (batch, output row). Rows 0..2 = xyz, 3..130 =
// feature channels. Raw f32 passthrough of gathered values.
// -------------------------------------------------------------------------
__global__ void gather_kernel(const float* __restrict__ xyz,
                              const float* __restrict__ feat,
                              const int*   __restrict__ idx,
                              float*       __restrict__ out)
{
    const int blk = blockIdx.x;
    const int b = blk / (3 + C_);
    const int r = blk % (3 + C_);
    const int* idb = idx + b * M_;

    if (r < 3) {
        const float* src = xyz + ((size_t)b * 3 + r) * N_;
        float*       dst = out + ((size_t)b * 3 + r) * M_;
        for (int m = threadIdx.x; m < M_; m += blockDim.x)
            dst[m] = src[idb[m]];
    } else {
        const int c = r - 3;
        const float* src = feat + ((size_t)b * C_ + c) * N_;
        float*       dst = out + (size_t)B_ * 3 * M_ + ((size_t)b * C_ + c) * M_;
        for (int m = threadIdx.x; m < M_; m += blockDim.x)
            dst[m] = src[idb[m]];
    }
}

extern "C" void kernel_launch(void* const* d_in, const int* in_sizes, int n_in,
                              void* d_out, int out_size, void* d_ws, size_t ws_size,
                              hipStream_t stream)
{
    const float* xyz  = (const float*)d_in[0];   // [16, 3, 16384] f32
    const float* feat = (const float*)d_in[1];   // [16, 128, 16384] f32
    float* out = (float*)d_out;                  // [16*3*4096] + [16*128*4096] f32
    int*   idx = (int*)d_ws;                     // [16, 4096] int32 scratch

    fps_kernel<<<dim3(B_), dim3(TPB), 0, stream>>>(xyz, idx);
    gather_kernel<<<dim3(B_ * (3 + C_)), dim3(256), 0, stream>>>(xyz, feat, idx, out);
}

// Round 18
// 5233.376 us; speedup vs baseline: 1.6651x; 1.3723x over previous
//
#include <hip/hip_runtime.h>

// DownSampling: B=16, N=16384, C=128, M=4096. f32 in/out.
// LOCKED ORACLE SEMANTICS (R14, absmax==0): per point,
//   dx=px-cx; dy=py-cy; dz=pz-cz;
//   d = fma(dz,dz, fma(dx,dx, rn(dy*dy)))   [XLA-GPU tree contraction]
//   dist = min(dist, d); argmax = (max value, MIN index).
// R18: active-CU VALU datapath ~95% busy (R17) and packed ops don't raise
// f32 throughput (R15/R16) -> cut real ops: inner loop tracks VALUE max only
// (1 op/pt vs 3); reduces carry value only (2 ops/level vs 5); the index is
// recovered post-reduce by the (rare) matching thread(s) via a descending
// equality scan + LDS atomicMin (global first-index tie-break preserved).
// 4-deep LDS rings make resets race-free; 2 barriers/iter.
#define B_   16
#define N_   16384
#define C_   128
#define M_   4096
#define TPB  1024
#define PPT  16   // points per thread: TPB*PPT == N_

#define DPP_QUAD_XOR1   0xB1   // quad_perm [1,0,3,2]
#define DPP_QUAD_XOR2   0x4E   // quad_perm [2,3,0,1]
#define DPP_HALF_MIRROR 0x141  // mirror within 8-lane half-rows
#define DPP_ROW_MIRROR  0x140  // mirror within 16-lane rows
#define SWZ_XOR16       0x401F // BitMode xor-16 within 32-lane groups

// value-only max join via DPP (VALU pipe)
#define VMAX_DPP(V, CTRL) do{                                                      \
    float _o = __int_as_float(__builtin_amdgcn_mov_dpp(__float_as_int(V),          \
                                                       (CTRL), 0xF, 0xF, 0));      \
    (V) = fmaxf((V), _o);                                                          \
}while(0)

// value-only max join via ds_swizzle xor pattern
#define VMAX_SWZ(V, PAT) do{                                                       \
    float _o = __int_as_float(__builtin_amdgcn_ds_swizzle(__float_as_int(V), PAT));\
    (V) = fmaxf((V), _o);                                                          \
}while(0)

__global__ __launch_bounds__(TPB, 4) void fps_kernel(const float* __restrict__ xyz,
                                                     int* __restrict__ idx_out)
{
    const int b = blockIdx.x;
    const int t = threadIdx.x;
    const int wid  = t >> 6;
    const int lane = t & 63;
    const float* xb = xyz + (size_t)b * 3 * N_;

    float px[PPT], py[PPT], pz[PPT], dist[PPT];

    // Load 16 consecutive points per thread (float4-vectorized, coalesced).
    {
        const float4* x4 = reinterpret_cast<const float4*>(xb);
        const float4* y4 = reinterpret_cast<const float4*>(xb + N_);
        const float4* z4 = reinterpret_cast<const float4*>(xb + 2 * N_);
        #pragma unroll
        for (int q = 0; q < 4; ++q) {
            float4 vx = x4[t * 4 + q];
            float4 vy = y4[t * 4 + q];
            float4 vz = z4[t * 4 + q];
            px[q*4+0] = vx.x; px[q*4+1] = vx.y; px[q*4+2] = vx.z; px[q*4+3] = vx.w;
            py[q*4+0] = vy.x; py[q*4+1] = vy.y; py[q*4+2] = vy.z; py[q*4+3] = vy.w;
            pz[q*4+0] = vz.x; pz[q*4+1] = vz.y; pz[q*4+2] = vz.z; pz[q*4+3] = vz.w;
        }
    }
    #pragma unroll
    for (int i = 0; i < PPT; ++i) dist[i] = 1e10f;  // BIG sentinel

    __shared__ float lv[4][16];   // per-wave value partials (4-ring)
    __shared__ int   widx[4];     // winning-index word per ring

    if (t < 4) widx[t] = 0x7fffffff;   // init rings; visible after barrier B1(m=1)

    if (t == 0) idx_out[b * M_ + 0] = 0;   // deterministic start at index 0

    // First centroid = point 0.
    float cx = xb[0], cy = xb[N_], cz = xb[2 * N_];

    for (int m = 1; m < M_; ++m) {
        const int buf = m & 3;

        // ---- a: distance update (locked semantics) + VALUE max only
        float vmax = -1.0f;
        #pragma unroll
        for (int i = 0; i < PPT; ++i) {
            float dx = __fsub_rn(px[i], cx);
            float dy = __fsub_rn(py[i], cy);
            float dz = __fsub_rn(pz[i], cz);
            float inner = fmaf(dx, dx, __fmul_rn(dy, dy));
            float d     = fmaf(dz, dz, inner);
            float nd = fminf(dist[i], d);
            dist[i] = nd;
            vmax = fmaxf(vmax, nd);
        }
        const float lmax = vmax;   // keep pre-reduce local max for match test

        // ---- b: wave value-reduce (4 DPP + xor16 swizzle + xor32 shfl)
        VMAX_DPP(vmax, DPP_QUAD_XOR1);
        VMAX_DPP(vmax, DPP_QUAD_XOR2);
        VMAX_DPP(vmax, DPP_HALF_MIRROR);
        VMAX_DPP(vmax, DPP_ROW_MIRROR);
        VMAX_SWZ(vmax, SWZ_XOR16);
        vmax = fmaxf(vmax, __shfl_xor(vmax, 32));

        // ---- c: publish wave partial; reset ring for iter m+2 (barrier-safe)
        if (lane == 0) lv[buf][wid] = vmax;
        if (t == 0) widx[(m + 2) & 3] = 0x7fffffff;
        __syncthreads();   // B1

        // ---- d: block value-reduce (16 partials, pure DPP within 16-lane row)
        float v2 = (lane < 16) ? lv[buf][lane] : -1.0f;
        VMAX_DPP(v2, DPP_QUAD_XOR1);
        VMAX_DPP(v2, DPP_QUAD_XOR2);
        VMAX_DPP(v2, DPP_HALF_MIRROR);
        VMAX_DPP(v2, DPP_ROW_MIRROR);
        const float bmax = __int_as_float(
            __builtin_amdgcn_readfirstlane(__float_as_int(v2)));

        // ---- e: rare index-find (only matching thread(s); waves skip via execz)
        if (lmax == bmax) {
            int cand = 0;
            #pragma unroll
            for (int i = PPT - 1; i >= 0; --i)      // descending: smallest slot wins
                cand = (dist[i] == bmax) ? i : cand;
            atomicMin(&widx[buf], t * PPT + cand);  // global MIN index (tie-break)
        }
        __syncthreads();   // B2

        // ---- f: read winner, emit, reload centroid (uniform)
        const int j = __builtin_amdgcn_readfirstlane(widx[buf]);
        if (t == 0) idx_out[b * M_ + m] = j;
        cx = xb[j];
        cy = xb[N_ + j];
        cz = xb[2 * N_ + j];
    }
}

// -------------------------------------------------------------------------
// Gather kernel: one block per (batch, output row). Rows 0..2 = xyz, 3..130 =
// feature channels. Raw f32 passthrough of gathered values.
// -------------------------------------------------------------------------
__global__ void gather_kernel(const float* __restrict__ xyz,
                              const float* __restrict__ feat,
                              const int*   __restrict__ idx,
                              float*       __restrict__ out)
{
    const int blk = blockIdx.x;
    const int b = blk / (3 + C_);
    const int r = blk % (3 + C_);
    const int* idb = idx + b * M_;

    if (r < 3) {
        const float* src = xyz + ((size_t)b * 3 + r) * N_;
        float*       dst = out + ((size_t)b * 3 + r) * M_;
        for (int m = threadIdx.x; m < M_; m += blockDim.x)
            dst[m] = src[idb[m]];
    } else {
        const int c = r - 3;
        const float* src = feat + ((size_t)b * C_ + c) * N_;
        float*       dst = out + (size_t)B_ * 3 * M_ + ((size_t)b * C_ + c) * M_;
        for (int m = threadIdx.x; m < M_; m += blockDim.x)
            dst[m] = src[idb[m]];
    }
}

extern "C" void kernel_launch(void* const* d_in, const int* in_sizes, int n_in,
                              void* d_out, int out_size, void* d_ws, size_t ws_size,
                              hipStream_t stream)
{
    const float* xyz  = (const float*)d_in[0];   // [16, 3, 16384] f32
    const float* feat = (const float*)d_in[1];   // [16, 128, 16384] f32
    float* out = (float*)d_out;                  // [16*3*4096] + [16*128*4096] f32
    int*   idx = (int*)d_ws;                     // [16, 4096] int32 scratch

    fps_kernel<<<dim3(B_), dim3(TPB), 0, stream>>>(xyz, idx);
    gather_kernel<<<dim3(B_ * (3 + C_)), dim3(256), 0, stream>>>(xyz, feat, idx, out);
}

// Round 19
// 5143.654 us; speedup vs baseline: 1.6942x; 1.0174x over previous
//
#include <hip/hip_runtime.h>

// DownSampling: B=16, N=16384, C=128, M=4096. f32 in/out.
// LOCKED ORACLE SEMANTICS (R14, absmax==0): per point,
//   dx=px-cx; dy=py-cy; dz=pz-cz;
//   d = fma(dz,dz, fma(dx,dx, rn(dy*dy)))   [XLA-GPU tree contraction]
//   dist = min(dist, d); argmax = (max value, MIN index).
// R19 = R18 + (a) v_max3 pairing for the value-max tracking (exact; 1 inst
// per 2 points) and (b) a 127.5KB dynamic-LDS cache of the first 10880
// points' coords: 66% of centroid reloads become ~70cyc ds_read broadcasts
// instead of ~200cyc dependent L2 loads on the serial critical path.
// Issue-cycle model (validated R17->R18 1:1): predict ~-175 cyc/iter.
#define B_   16
#define N_   16384
#define C_   128
#define M_   4096
#define TPB  1024
#define PPT  16    // points per thread: TPB*PPT == N_
#define NC   10880 // points with coords cached in LDS (3*NC*4 = 130560 B)

#define DPP_QUAD_XOR1   0xB1   // quad_perm [1,0,3,2]
#define DPP_QUAD_XOR2   0x4E   // quad_perm [2,3,0,1]
#define DPP_HALF_MIRROR 0x141  // mirror within 8-lane half-rows
#define DPP_ROW_MIRROR  0x140  // mirror within 16-lane rows
#define SWZ_XOR16       0x401F // BitMode xor-16 within 32-lane groups

// value-only max join via DPP (VALU pipe)
#define VMAX_DPP(V, CTRL) do{                                                      \
    float _o = __int_as_float(__builtin_amdgcn_mov_dpp(__float_as_int(V),          \
                                                       (CTRL), 0xF, 0xF, 0));      \
    (V) = fmaxf((V), _o);                                                          \
}while(0)

// value-only max join via ds_swizzle xor pattern
#define VMAX_SWZ(V, PAT) do{                                                       \
    float _o = __int_as_float(__builtin_amdgcn_ds_swizzle(__float_as_int(V), PAT));\
    (V) = fmaxf((V), _o);                                                          \
}while(0)

__global__ __launch_bounds__(TPB, 4) void fps_kernel(const float* __restrict__ xyz,
                                                     int* __restrict__ idx_out)
{
    const int b = blockIdx.x;
    const int t = threadIdx.x;
    const int wid  = t >> 6;
    const int lane = t & 63;
    const float* xb = xyz + (size_t)b * 3 * N_;

    extern __shared__ float smem[];          // dynamic: coord cache
    float* cX = smem;
    float* cY = smem + NC;
    float* cZ = smem + 2 * NC;

    float px[PPT], py[PPT], pz[PPT], dist[PPT];

    // Load 16 consecutive points per thread (float4-vectorized, coalesced).
    {
        const float4* x4 = reinterpret_cast<const float4*>(xb);
        const float4* y4 = reinterpret_cast<const float4*>(xb + N_);
        const float4* z4 = reinterpret_cast<const float4*>(xb + 2 * N_);
        #pragma unroll
        for (int q = 0; q < 4; ++q) {
            float4 vx = x4[t * 4 + q];
            float4 vy = y4[t * 4 + q];
            float4 vz = z4[t * 4 + q];
            px[q*4+0] = vx.x; px[q*4+1] = vx.y; px[q*4+2] = vx.z; px[q*4+3] = vx.w;
            py[q*4+0] = vy.x; py[q*4+1] = vy.y; py[q*4+2] = vy.z; py[q*4+3] = vy.w;
            pz[q*4+0] = vz.x; pz[q*4+1] = vz.y; pz[q*4+2] = vz.z; pz[q*4+3] = vz.w;
        }
    }
    #pragma unroll
    for (int i = 0; i < PPT; ++i) dist[i] = 1e10f;  // BIG sentinel

    // Fill LDS coord cache (one-time; visible by first use via iter-1 barriers).
    for (int p = t; p < NC; p += TPB) {
        cX[p] = xb[p];
        cY[p] = xb[N_ + p];
        cZ[p] = xb[2 * N_ + p];
    }

    __shared__ float lv[4][16];   // per-wave value partials (4-ring)
    __shared__ int   widx[4];     // winning-index word per ring

    if (t < 4) widx[t] = 0x7fffffff;   // init rings; visible after B1(m=1)

    if (t == 0) idx_out[b * M_ + 0] = 0;   // deterministic start at index 0

    // First centroid = point 0.
    float cx = xb[0], cy = xb[N_], cz = xb[2 * N_];

    for (int m = 1; m < M_; ++m) {
        const int buf = m & 3;

        // ---- a: distance update (locked semantics) + value max (max3 pairs)
        float vmax = -1.0f;
        #pragma unroll
        for (int i = 0; i < PPT; i += 2) {
            float dx0 = __fsub_rn(px[i], cx);
            float dy0 = __fsub_rn(py[i], cy);
            float dz0 = __fsub_rn(pz[i], cz);
            float d0  = fmaf(dz0, dz0, fmaf(dx0, dx0, __fmul_rn(dy0, dy0)));
            float n0  = fminf(dist[i], d0);
            dist[i] = n0;
            float dx1 = __fsub_rn(px[i+1], cx);
            float dy1 = __fsub_rn(py[i+1], cy);
            float dz1 = __fsub_rn(pz[i+1], cz);
            float d1  = fmaf(dz1, dz1, fmaf(dx1, dx1, __fmul_rn(dy1, dy1)));
            float n1  = fminf(dist[i+1], d1);
            dist[i+1] = n1;
            vmax = fmaxf(fmaxf(vmax, n0), n1);   // fuses to v_max3_f32 (exact)
        }
        const float lmax = vmax;   // pre-reduce local max for match test

        // ---- b: wave value-reduce (4 DPP + xor16 swizzle + xor32 shfl)
        VMAX_DPP(vmax, DPP_QUAD_XOR1);
        VMAX_DPP(vmax, DPP_QUAD_XOR2);
        VMAX_DPP(vmax, DPP_HALF_MIRROR);
        VMAX_DPP(vmax, DPP_ROW_MIRROR);
        VMAX_SWZ(vmax, SWZ_XOR16);
        vmax = fmaxf(vmax, __shfl_xor(vmax, 32));

        // ---- c: publish wave partial; reset ring for iter m+2 (barrier-safe)
        if (lane == 0) lv[buf][wid] = vmax;
        if (t == 0) widx[(m + 2) & 3] = 0x7fffffff;
        __syncthreads();   // B1

        // ---- d: block value-reduce (16 partials, pure DPP within 16-lane row)
        float v2 = (lane < 16) ? lv[buf][lane] : -1.0f;
        VMAX_DPP(v2, DPP_QUAD_XOR1);
        VMAX_DPP(v2, DPP_QUAD_XOR2);
        VMAX_DPP(v2, DPP_HALF_MIRROR);
        VMAX_DPP(v2, DPP_ROW_MIRROR);
        const float bmax = __int_as_float(
            __builtin_amdgcn_readfirstlane(__float_as_int(v2)));

        // ---- e: rare index-find (only matching thread(s); waves skip via execz)
        if (lmax == bmax) {
            int cand = 0;
            #pragma unroll
            for (int i = PPT - 1; i >= 0; --i)      // descending: smallest slot wins
                cand = (dist[i] == bmax) ? i : cand;
            atomicMin(&widx[buf], t * PPT + cand);  // global MIN index (tie-break)
        }
        __syncthreads();   // B2

        // ---- f: read winner, emit, reload centroid (LDS-cached or VMEM)
        const int j = __builtin_amdgcn_readfirstlane(widx[buf]);
        if (t == 0) idx_out[b * M_ + m] = j;
        if (j < NC) {   // uniform scalar branch; ds_read broadcast (~70cyc)
            cx = cX[j];
            cy = cY[j];
            cz = cZ[j];
        } else {        // fallback: L2 loads (~200cyc), 34% of iterations
            cx = xb[j];
            cy = xb[N_ + j];
            cz = xb[2 * N_ + j];
        }
    }
}

// -------------------------------------------------------------------------
// Gather kernel: one block per (batch, output row). Rows 0..2 = xyz, 3..130 =
// feature channels. Raw f32 passthrough of gathered values.
// -------------------------------------------------------------------------
__global__ void gather_kernel(const float* __restrict__ xyz,
                              const float* __restrict__ feat,
                              const int*   __restrict__ idx,
                              float*       __restrict__ out)
{
    const int blk = blockIdx.x;
    const int b = blk / (3 + C_);
    const int r = blk % (3 + C_);
    const int* idb = idx + b * M_;

    if (r < 3) {
        const float* src = xyz + ((size_t)b * 3 + r) * N_;
        float*       dst = out + ((size_t)b * 3 + r) * M_;
        for (int m = threadIdx.x; m < M_; m += blockDim.x)
            dst[m] = src[idb[m]];
    } else {
        const int c = r - 3;
        const float* src = feat + ((size_t)b * C_ + c) * N_;
        float*       dst = out + (size_t)B_ * 3 * M_ + ((size_t)b * C_ + c) * M_;
        for (int m = threadIdx.x; m < M_; m += blockDim.x)
            dst[m] = src[idb[m]];
    }
}

extern "C" void kernel_launch(void* const* d_in, const int* in_sizes, int n_in,
                              void* d_out, int out_size, void* d_ws, size_t ws_size,
                              hipStream_t stream)
{
    const float* xyz  = (const float*)d_in[0];   // [16, 3, 16384] f32
    const float* feat = (const float*)d_in[1];   // [16, 128, 16384] f32
    float* out = (float*)d_out;                  // [16*3*4096] + [16*128*4096] f32
    int*   idx = (int*)d_ws;                     // [16, 4096] int32 scratch

    const size_t dyn_lds = (size_t)3 * NC * sizeof(float);   // 130560 B
    fps_kernel<<<dim3(B_), dim3(TPB), dyn_lds, stream>>>(xyz, idx);
    gather_kernel<<<dim3(B_ * (3 + C_)), dim3(256), 0, stream>>>(xyz, feat, idx, out);
}